// Round 7
// baseline (306.692 us; speedup 1.0000x reference)
//
#include <hip/hip_runtime.h>
#include <hip/hip_bf16.h>
#include <math.h>

#define B_SZ 16
#define T_SZ 128
#define N_P 12
#define D_SZ 1024
#define D2_SZ 2048
#define BT 2048          // B*T tokens
#define KDIM 2048        // inner dim of projections (2D)
#define EALL 8192        // 4*1024 (tb,pb,ta,pa) + 2*2048 (gb,ga)
#define EPROJ 4096       // tb|pb|ta|pa row width

typedef __attribute__((ext_vector_type(8))) short short8;    // 8 bf16 = 4 VGPRs
typedef __attribute__((ext_vector_type(4))) float floatx4;   // MFMA C/D

__device__ inline void gload_lds16(const void* g, void* l) {
  __builtin_amdgcn_global_load_lds(
      (const __attribute__((address_space(1))) void*)g,
      (__attribute__((address_space(3))) void*)l, 16, 0, 0);
}

__device__ inline unsigned short f2bf(float x) {
  union { __hip_bfloat16 h; unsigned short u; } cv;
  cv.h = __float2bfloat16(x);
  return cv.u;
}
__device__ inline float bf2f(unsigned short u) {
  return __uint_as_float(((unsigned)u) << 16);
}

// ---------------------------------------------------------------------------
// Kernel 1 (merged): blocks [0, BT) build n = [g ; max] per token;
// blocks [BT, BT+12288) convert the 6 weight matrices to bf16.
// Wb row order: [tb | pb | ta | pa | gb | ga]
// ---------------------------------------------------------------------------
__global__ __launch_bounds__(256) void prep_kernel(
    const float* __restrict__ feat, const float* __restrict__ Wq,
    const float* __restrict__ Wtb, const float* __restrict__ Wpb,
    const float* __restrict__ Wta, const float* __restrict__ Wpa,
    const float* __restrict__ Wgb, const float* __restrict__ Wga,
    unsigned short* __restrict__ Nbf, unsigned short* __restrict__ Wb) {
  const int bid = blockIdx.x;
  const int tid = threadIdx.x;
  if (bid < BT) {
    // ---------------- build_n ----------------
    const int t = bid;
    const float4* fb4 = (const float4*)(feat + (size_t)t * N_P * D_SZ);
    const float4* wq4 = (const float4*)Wq;

    float4 q = {0.f, 0.f, 0.f, 0.f};
#pragma unroll
    for (int m = 0; m < N_P; ++m) {
      const float4 v = wq4[m * 256 + tid];
      q.x += v.x; q.y += v.y; q.z += v.z; q.w += v.w;
    }

    float4 fv[N_P];
    float part[N_P];
#pragma unroll
    for (int n = 0; n < N_P; ++n) {
      const float4 f = fb4[n * 256 + tid];
      fv[n] = f;
      part[n] = f.x * q.x + f.y * q.y + f.z * q.z + f.w * q.w;
    }

    __shared__ float wred[N_P * 4];
    const int lane = tid & 63;
    const int wave = tid >> 6;
#pragma unroll
    for (int n = 0; n < N_P; ++n) {
      float v = part[n];
#pragma unroll
      for (int off = 32; off; off >>= 1) v += __shfl_down(v, off);
      if (lane == 0) wred[n * 4 + wave] = v;
    }
    __syncthreads();

    float w[N_P];
#pragma unroll
    for (int n = 0; n < N_P; ++n)
      w[n] = wred[n * 4 + 0] + wred[n * 4 + 1] + wred[n * 4 + 2] +
             wred[n * 4 + 3];

    float4 g = {0.f, 0.f, 0.f, 0.f};
    float4 fm = {-INFINITY, -INFINITY, -INFINITY, -INFINITY};
#pragma unroll
    for (int n = 0; n < N_P; ++n) {
      const float4 f = fv[n];
      g.x += w[n] * f.x; g.y += w[n] * f.y; g.z += w[n] * f.z;
      g.w += w[n] * f.w;
      fm.x = fmaxf(fm.x, f.x); fm.y = fmaxf(fm.y, f.y);
      fm.z = fmaxf(fm.z, f.z); fm.w = fmaxf(fm.w, f.w);
    }
    ushort4 og, of;
    og.x = f2bf(g.x); og.y = f2bf(g.y); og.z = f2bf(g.z); og.w = f2bf(g.w);
    of.x = f2bf(fm.x); of.y = f2bf(fm.y); of.z = f2bf(fm.z); of.w = f2bf(fm.w);
    *(ushort4*)&Nbf[(size_t)t * D2_SZ + tid * 4] = og;
    *(ushort4*)&Nbf[(size_t)t * D2_SZ + D_SZ + tid * 4] = of;
  } else {
    // ---------------- weight conversion ----------------
    const int id = bid - BT;            // 0..12287
    const int r = id >> 11;             // 0..5
    const int xb = id & 2047;
    const int i = xb * 256 + tid;       // < 524288
    const float* src;
    size_t off;
    switch (r) {
      case 0: src = Wtb; off = 0; break;
      case 1: src = Wpb; off = (size_t)1024 * KDIM; break;
      case 2: src = Wta; off = (size_t)2048 * KDIM; break;
      case 3: src = Wpa; off = (size_t)3072 * KDIM; break;
      case 4: src = Wgb; off = (size_t)4096 * KDIM; break;
      default: src = Wga; off = (size_t)6144 * KDIM; break;
    }
    {
      const float4 v = ((const float4*)src)[i];
      ushort4 o;
      o.x = f2bf(v.x); o.y = f2bf(v.y); o.z = f2bf(v.z); o.w = f2bf(v.w);
      ((ushort4*)(Wb + off))[i] = o;
    }
    if (r >= 4) {
      const int i2 = i + 524288;
      const float4 v = ((const float4*)src)[i2];
      ushort4 o;
      o.x = f2bf(v.x); o.y = f2bf(v.y); o.z = f2bf(v.z); o.w = f2bf(v.w);
      ((ushort4*)(Wb + off))[i2] = o;
    }
  }
}

// ---------------------------------------------------------------------------
// Kernel B: fused projection GEMM, bf16 MFMA.
// NEW: 128x256 tile, grid 512 = 2 blocks/CU (occupancy mechanism: while one
// block waits at its step barrier/vmcnt, the other computes — m97's implicit
// overlap). 512 thr (8 waves 2Mx4N, wave tile 64x64), BK=32, ring-of-3 LDS
// (72 KiB/block -> 144/CU), prefetch distance 2, counted vmcnt(3) (T4),
// XOR bank swizzle (T2), XCD swizzle (T1), setprio (T5).
// Ledger: 3 gload_lds/thread/step. Outstanding at wait point of step t:
//   {t+1:3 (issued t-1), t+2:3 (issued t)} = 6 -> vmcnt(3) = slot t+1 landed.
// Tail: t=62 -> vmcnt(0); t=63 -> none. Barrier after wait makes the landing
// workgroup-wide. WAR: STAGE(t+2) reuses slot of t-1, whose ds_reads drained
// (data in regs before MFMA) before the end-of-(t-1) barrier.
// ---------------------------------------------------------------------------
__global__ __launch_bounds__(512, 4) void gemm_fused(
    const unsigned short* __restrict__ X,
    const unsigned short* __restrict__ Wb,
    unsigned short* __restrict__ Cproj,
    unsigned short* __restrict__ Gbt,
    unsigned short* __restrict__ Gat) {
  __shared__ __align__(16) unsigned short lds[3 * 12288];  // 72 KiB ring-3
  const int tid = threadIdx.x;
  const int lane = tid & 63;
  const int w = tid >> 6;           // 0..7
  const int quad = lane >> 4;
  const int l15 = lane & 15;
  const int wm = (w >> 2) * 64;     // 2 waves in M (wave tile 64 rows)
  const int wn = (w & 3) * 64;      // 4 waves in N

  // XCD swizzle: 512 blocks, 8 XCDs, 64/XCD -> e-tiles {4k..4k+3} per XCD
  // (4 MB of B L2-resident), all 16 m-tiles.
  const int bid = blockIdx.x;
  const int swz = (bid & 7) * 64 + (bid >> 3);
  const int m0 = (swz & 15) * 128;  // token tile
  const int be = swz >> 4;          // 0..31 E-tile
  const int e0 = be * 256;

  floatx4 acc[4][4];
#pragma unroll
  for (int mt = 0; mt < 4; ++mt)
#pragma unroll
    for (int nt = 0; nt < 4; ++nt) {
      floatx4 z = {0.f, 0.f, 0.f, 0.f};
      acc[mt][nt] = z;
    }

  // A staging: 512 slots (128 rows x 4 chunks), 1 per thread.
  const unsigned short* srcA;
  int dstA;
  {
    const int s = tid;
    const int row = s >> 2;                    // 0..127
    const int ccg = (s & 3) ^ ((row >> 1) & 3);
    srcA = X + (size_t)(m0 + row) * KDIM + ccg * 8;
    dstA = s * 8;
  }
  // B staging: 1024 slots (256 rows x 4 chunks), 2 per thread.
  const unsigned short* srcB[2];
  int dstB[2];
#pragma unroll
  for (int c = 0; c < 2; ++c) {
    const int s = tid + c * 512;
    const int row = s >> 2;                    // 0..255
    const int ccg = (s & 3) ^ ((row >> 1) & 3);
    srcB[c] = Wb + (size_t)(e0 + row) * KDIM + ccg * 8;
    dstB[c] = 4096 + s * 8;                    // B region after A's 4096 shorts
  }

  // loop-invariant swizzled fragment offsets (ushorts within a 24KB slot)
  int aofs[4], bofs[4];
#pragma unroll
  for (int mt = 0; mt < 4; ++mt) {
    const int row = wm + mt * 16 + l15;        // 0..127
    aofs[mt] = row * 32 + ((quad ^ ((row >> 1) & 3)) * 8);
  }
#pragma unroll
  for (int nt = 0; nt < 4; ++nt) {
    const int row = wn + nt * 16 + l15;        // 0..255
    bofs[nt] = 4096 + row * 32 + ((quad ^ ((row >> 1) & 3)) * 8);
  }

  auto STAGE = [&](int t, int sb) {
    const int k0_ = t * 32;
    gload_lds16(srcA + k0_, &lds[sb + dstA]);
    gload_lds16(srcB[0] + k0_, &lds[sb + dstB[0]]);
    gload_lds16(srcB[1] + k0_, &lds[sb + dstB[1]]);
  };

  int s0 = 0, s1 = 12288, s2 = 24576;   // slots for t, t+1, t+2

  // prologue: stage slots 0,1 (6 loads); vmcnt(3) -> slot 0 landed.
  STAGE(0, s0); STAGE(1, s1);
  __builtin_amdgcn_sched_barrier(0);
  asm volatile("s_waitcnt vmcnt(3)" ::: "memory");
  __builtin_amdgcn_sched_barrier(0);
  __builtin_amdgcn_s_barrier();
  __builtin_amdgcn_sched_barrier(0);

  for (int t = 0; t < 64; ++t) {            // KDIM/32 = 64 steps
    short8 a[4], b[4];
#pragma unroll
    for (int mt = 0; mt < 4; ++mt) a[mt] = *(const short8*)&lds[s0 + aofs[mt]];
#pragma unroll
    for (int nt = 0; nt < 4; ++nt) b[nt] = *(const short8*)&lds[s0 + bofs[nt]];
    if (t + 2 < 64) STAGE(t + 2, s2);
    __builtin_amdgcn_s_setprio(1);
#pragma unroll
    for (int mt = 0; mt < 4; ++mt)
#pragma unroll
      for (int nt = 0; nt < 4; ++nt)
        acc[mt][nt] = __builtin_amdgcn_mfma_f32_16x16x32_bf16(
            a[mt], b[nt], acc[mt][nt], 0, 0, 0);
    __builtin_amdgcn_s_setprio(0);
    __builtin_amdgcn_sched_barrier(0);
    if (t + 2 < 64) {
      asm volatile("s_waitcnt vmcnt(3)" ::: "memory");
    } else if (t + 1 < 64) {
      asm volatile("s_waitcnt vmcnt(0)" ::: "memory");
    }
    __builtin_amdgcn_sched_barrier(0);
    if (t + 1 < 64) {
      __builtin_amdgcn_s_barrier();
      __builtin_amdgcn_sched_barrier(0);
    }
    const int tmp = s0; s0 = s1; s1 = s2; s2 = tmp;   // rotate ring
  }

  if (be < 16) {
#pragma unroll
    for (int mt = 0; mt < 4; ++mt)
#pragma unroll
      for (int nt = 0; nt < 4; ++nt) {
        const int col = e0 + wn + nt * 16 + l15;
#pragma unroll
        for (int r = 0; r < 4; ++r) {
          const int rowg = m0 + wm + mt * 16 + quad * 4 + r;
          Cproj[(size_t)rowg * EPROJ + col] = f2bf(acc[mt][nt][r]);
        }
      }
  } else {
    unsigned short* Gt = (be < 24) ? Gbt : Gat;
    const int fb = e0 - ((be < 24) ? 4096 : 6144);
#pragma unroll
    for (int mt = 0; mt < 4; ++mt)
#pragma unroll
      for (int nt = 0; nt < 4; ++nt) {
        const int f = fb + wn + nt * 16 + l15;
        const int tok0 = m0 + wm + mt * 16 + quad * 4;
        ushort4 o;
        o.x = f2bf(acc[mt][nt][0]); o.y = f2bf(acc[mt][nt][1]);
        o.z = f2bf(acc[mt][nt][2]); o.w = f2bf(acc[mt][nt][3]);
        *(ushort4*)&Gt[(size_t)f * BT + tok0] = o;
      }
  }
}

// ---------------------------------------------------------------------------
// Kernel 3: fused score. grid (16 batches, 2 branches, 2 j-chunks).
// Each block: 128(i) x 64(j) S-tile, full K=1024, epilogue mask+scale+bf16.
// ---------------------------------------------------------------------------
__global__ __launch_bounds__(256) void score_direct(
    const unsigned short* __restrict__ Cproj, unsigned short* __restrict__ Sbf) {
  const int b = blockIdx.x;
  const int br = blockIdx.y;
  const int jc = blockIdx.z;
  const int aoff = br ? 2048 : 0;   // ta : tb
  const int boff = aoff + 1024;     // pa : pb
  const int t0 = b * T_SZ;
  const int j0 = jc * 64;

  __shared__ __align__(16) unsigned short As[128 * 32];   // 8 KB
  __shared__ __align__(16) unsigned short Bs[64 * 32];    // 4 KB
  const int tid = threadIdx.x;
  const int lane = tid & 63;
  const int w = tid >> 6;
  const int wm = (w >> 1) * 64;    // i-offset (2 waves in M)
  const int wn = (w & 1) * 32;     // j-offset (2 waves in N)
  const int quad = lane >> 4;
  const int l15 = lane & 15;

  floatx4 acc[4][2];
#pragma unroll
  for (int mt = 0; mt < 4; ++mt)
#pragma unroll
    for (int nt = 0; nt < 2; ++nt) {
      floatx4 z = {0.f, 0.f, 0.f, 0.f};
      acc[mt][nt] = z;
    }

  const unsigned short* gA[2];
  unsigned short* lA[2];
#pragma unroll
  for (int c = 0; c < 2; ++c) {
    const int s = tid + c * 256;
    const int row = s >> 2;
    const int ccg = (s & 3) ^ ((row >> 1) & 3);
    gA[c] = Cproj + (size_t)(t0 + row) * EPROJ + aoff + ccg * 8;
    lA[c] = &As[(size_t)s * 8];
  }
  const unsigned short* gB;
  unsigned short* lB;
  {
    const int s = tid;
    const int row = s >> 2;
    const int ccg = (s & 3) ^ ((row >> 1) & 3);
    gB = Cproj + (size_t)(t0 + j0 + row) * EPROJ + boff + ccg * 8;
    lB = &Bs[(size_t)s * 8];
  }

  int aofs[4], bofs[2];
#pragma unroll
  for (int mt = 0; mt < 4; ++mt) {
    const int row = wm + mt * 16 + l15;
    aofs[mt] = row * 32 + ((quad ^ ((row >> 1) & 3)) * 8);
  }
#pragma unroll
  for (int nt = 0; nt < 2; ++nt) {
    const int row = wn + nt * 16 + l15;
    bofs[nt] = row * 32 + ((quad ^ ((row >> 1) & 3)) * 8);
  }

  for (int k0 = 0; k0 < D_SZ; k0 += 32) {   // K = 1024, 32 steps
    gload_lds16(gA[0] + k0, lA[0]);
    gload_lds16(gA[1] + k0, lA[1]);
    gload_lds16(gB + k0, lB);
    __syncthreads();
    short8 a[4], bb[2];
#pragma unroll
    for (int mt = 0; mt < 4; ++mt) a[mt] = *(const short8*)&As[aofs[mt]];
#pragma unroll
    for (int nt = 0; nt < 2; ++nt) bb[nt] = *(const short8*)&Bs[bofs[nt]];
#pragma unroll
    for (int mt = 0; mt < 4; ++mt)
#pragma unroll
      for (int nt = 0; nt < 2; ++nt)
        acc[mt][nt] = __builtin_amdgcn_mfma_f32_16x16x32_bf16(
            a[mt], bb[nt], acc[mt][nt], 0, 0, 0);
    __syncthreads();
  }

  const float scale = 0.022097086912079608f;  // 1/sqrt(2*1024)
  unsigned short* Sp = Sbf + ((size_t)(br * B_SZ + b)) * T_SZ * T_SZ;
#pragma unroll
  for (int mt = 0; mt < 4; ++mt)
#pragma unroll
    for (int nt = 0; nt < 2; ++nt) {
      const int j = j0 + wn + nt * 16 + l15;
#pragma unroll
      for (int r = 0; r < 4; ++r) {
        const int i = wm + mt * 16 + quad * 4 + r;
        const bool keep = br ? (j > i) : (j < i);
        Sp[(size_t)i * T_SZ + j] = f2bf(keep ? acc[mt][nt][r] * scale : 0.f);
      }
    }
}

// ---------------------------------------------------------------------------
// Kernel D: PV via MFMA, no LDS.
// ---------------------------------------------------------------------------
__global__ __launch_bounds__(256) void pv_mfma(
    const unsigned short* __restrict__ Nbf,
    const unsigned short* __restrict__ Sbf,
    const unsigned short* __restrict__ Gbt,
    const unsigned short* __restrict__ Gat,
    float* __restrict__ out) {
  const int ft = blockIdx.x;
  const int b = blockIdx.y;
  const int f0 = ft * 128;
  const int t0 = b * T_SZ;
  const int tid = threadIdx.x;
  const int lane = tid & 63;
  const int w = tid >> 6;
  const int wm = (w >> 1) * 64;   // token dim
  const int wn = (w & 1) * 64;    // f dim
  const int quad = lane >> 4;
  const int l15 = lane & 15;

  const unsigned short* Sb = Sbf + ((size_t)0 * B_SZ + b) * T_SZ * T_SZ;
  const unsigned short* Sa = Sbf + ((size_t)1 * B_SZ + b) * T_SZ * T_SZ;

  floatx4 acc[4][4];
#pragma unroll
  for (int mt = 0; mt < 4; ++mt)
#pragma unroll
    for (int nt = 0; nt < 4; ++nt) {
      floatx4 z = {0.f, 0.f, 0.f, 0.f};
      acc[mt][nt] = z;
    }

#pragma unroll
  for (int k0 = 0; k0 < T_SZ; k0 += 32) {
    short8 ab[4], aa[4], bb[4], ba[4];
#pragma unroll
    for (int mt = 0; mt < 4; ++mt) {
      const int i = wm + mt * 16 + l15;
      ab[mt] = *(const short8*)&Sb[(size_t)i * T_SZ + k0 + quad * 8];
      aa[mt] = *(const short8*)&Sa[(size_t)i * T_SZ + k0 + quad * 8];
    }
#pragma unroll
    for (int nt = 0; nt < 4; ++nt) {
      const int f = f0 + wn + nt * 16 + l15;
      bb[nt] = *(const short8*)&Gbt[(size_t)f * BT + t0 + k0 + quad * 8];
      ba[nt] = *(const short8*)&Gat[(size_t)f * BT + t0 + k0 + quad * 8];
    }
#pragma unroll
    for (int mt = 0; mt < 4; ++mt)
#pragma unroll
      for (int nt = 0; nt < 4; ++nt) {
        acc[mt][nt] = __builtin_amdgcn_mfma_f32_16x16x32_bf16(
            ab[mt], bb[nt], acc[mt][nt], 0, 0, 0);
        acc[mt][nt] = __builtin_amdgcn_mfma_f32_16x16x32_bf16(
            aa[mt], ba[nt], acc[mt][nt], 0, 0, 0);
      }
  }

#pragma unroll
  for (int mt = 0; mt < 4; ++mt)
#pragma unroll
    for (int nt = 0; nt < 4; ++nt) {
      const int f = f0 + wn + nt * 16 + l15;
#pragma unroll
      for (int r = 0; r < 4; ++r) {
        const int tok = t0 + wm + mt * 16 + quad * 4 + r;
        out[(size_t)tok * D2_SZ + f] =
            acc[mt][nt][r] + bf2f(Nbf[(size_t)tok * D2_SZ + f]);
      }
    }
}

// ---------------------------------------------------------------------------
extern "C" void kernel_launch(void* const* d_in, const int* in_sizes, int n_in,
                              void* d_out, int out_size, void* d_ws, size_t ws_size,
                              hipStream_t stream) {
  const float* feat = (const float*)d_in[0];
  const float* Wq  = (const float*)d_in[1];
  const float* Wtb = (const float*)d_in[2];
  const float* Wpb = (const float*)d_in[3];
  const float* Wgb = (const float*)d_in[4];  // dict order: gb before ta
  const float* Wta = (const float*)d_in[5];
  const float* Wpa = (const float*)d_in[6];
  const float* Wga = (const float*)d_in[7];
  float* out = (float*)d_out;

  unsigned short* ws = (unsigned short*)d_ws;
  unsigned short* Nbf   = ws;                                 // [2048][2048] bf16
  unsigned short* Wb    = Nbf + (size_t)BT * D2_SZ;           // [8192][2048] bf16
  unsigned short* Cproj = Wb + (size_t)EALL * KDIM;           // [2048][4096] bf16
  unsigned short* Gbt   = Cproj + (size_t)BT * EPROJ;         // [2048][2048] bf16
  unsigned short* Gat   = Gbt + (size_t)D2_SZ * BT;           // [2048][2048] bf16
  unsigned short* Sbf   = Gat + (size_t)D2_SZ * BT;           // [2][16][128][128] bf16

  prep_kernel<<<BT + 12288, 256, 0, stream>>>(feat, Wq, Wtb, Wpb, Wta, Wpa,
                                              Wgb, Wga, Nbf, Wb);
  gemm_fused<<<dim3(512), 512, 0, stream>>>(Nbf, Wb, Cproj, Gbt, Gat);
  score_direct<<<dim3(B_SZ, 2, 2), 256, 0, stream>>>(Cproj, Sbf);
  pv_mfma<<<dim3(D2_SZ / 128, B_SZ), 256, 0, stream>>>(Nbf, Sbf, Gbt, Gat, out);
}

// Round 8
// 294.148 us; speedup vs baseline: 1.0426x; 1.0426x over previous
//
#include <hip/hip_runtime.h>
#include <hip/hip_bf16.h>
#include <math.h>

#define B_SZ 16
#define T_SZ 128
#define N_P 12
#define D_SZ 1024
#define D2_SZ 2048
#define BT 2048          // B*T tokens
#define KDIM 2048        // inner dim of projections (2D)
#define EALL 8192        // 4*1024 (tb,pb,ta,pa) + 2*2048 (gb,ga)
#define EPROJ 4096       // tb|pb|ta|pa row width

typedef __attribute__((ext_vector_type(8))) short short8;    // 8 bf16 = 4 VGPRs
typedef __attribute__((ext_vector_type(4))) float floatx4;   // MFMA C/D

__device__ inline void gload_lds16(const void* g, void* l) {
  __builtin_amdgcn_global_load_lds(
      (const __attribute__((address_space(1))) void*)g,
      (__attribute__((address_space(3))) void*)l, 16, 0, 0);
}

__device__ inline unsigned short f2bf(float x) {
  union { __hip_bfloat16 h; unsigned short u; } cv;
  cv.h = __float2bfloat16(x);
  return cv.u;
}
__device__ inline float bf2f(unsigned short u) {
  return __uint_as_float(((unsigned)u) << 16);
}

// ---------------------------------------------------------------------------
// Kernel 1 (merged): blocks [0, BT) build n = [g ; max] per token;
// blocks [BT, BT+12288) convert the 6 weight matrices to bf16.
// Wb row order: [tb | pb | ta | pa | gb | ga]
// ---------------------------------------------------------------------------
__global__ __launch_bounds__(256) void prep_kernel(
    const float* __restrict__ feat, const float* __restrict__ Wq,
    const float* __restrict__ Wtb, const float* __restrict__ Wpb,
    const float* __restrict__ Wta, const float* __restrict__ Wpa,
    const float* __restrict__ Wgb, const float* __restrict__ Wga,
    unsigned short* __restrict__ Nbf, unsigned short* __restrict__ Wb) {
  const int bid = blockIdx.x;
  const int tid = threadIdx.x;
  if (bid < BT) {
    const int t = bid;
    const float4* fb4 = (const float4*)(feat + (size_t)t * N_P * D_SZ);
    const float4* wq4 = (const float4*)Wq;

    float4 q = {0.f, 0.f, 0.f, 0.f};
#pragma unroll
    for (int m = 0; m < N_P; ++m) {
      const float4 v = wq4[m * 256 + tid];
      q.x += v.x; q.y += v.y; q.z += v.z; q.w += v.w;
    }

    float4 fv[N_P];
    float part[N_P];
#pragma unroll
    for (int n = 0; n < N_P; ++n) {
      const float4 f = fb4[n * 256 + tid];
      fv[n] = f;
      part[n] = f.x * q.x + f.y * q.y + f.z * q.z + f.w * q.w;
    }

    __shared__ float wred[N_P * 4];
    const int lane = tid & 63;
    const int wave = tid >> 6;
#pragma unroll
    for (int n = 0; n < N_P; ++n) {
      float v = part[n];
#pragma unroll
      for (int off = 32; off; off >>= 1) v += __shfl_down(v, off);
      if (lane == 0) wred[n * 4 + wave] = v;
    }
    __syncthreads();

    float w[N_P];
#pragma unroll
    for (int n = 0; n < N_P; ++n)
      w[n] = wred[n * 4 + 0] + wred[n * 4 + 1] + wred[n * 4 + 2] +
             wred[n * 4 + 3];

    float4 g = {0.f, 0.f, 0.f, 0.f};
    float4 fm = {-INFINITY, -INFINITY, -INFINITY, -INFINITY};
#pragma unroll
    for (int n = 0; n < N_P; ++n) {
      const float4 f = fv[n];
      g.x += w[n] * f.x; g.y += w[n] * f.y; g.z += w[n] * f.z;
      g.w += w[n] * f.w;
      fm.x = fmaxf(fm.x, f.x); fm.y = fmaxf(fm.y, f.y);
      fm.z = fmaxf(fm.z, f.z); fm.w = fmaxf(fm.w, f.w);
    }
    ushort4 og, of;
    og.x = f2bf(g.x); og.y = f2bf(g.y); og.z = f2bf(g.z); og.w = f2bf(g.w);
    of.x = f2bf(fm.x); of.y = f2bf(fm.y); of.z = f2bf(fm.z); of.w = f2bf(fm.w);
    *(ushort4*)&Nbf[(size_t)t * D2_SZ + tid * 4] = og;
    *(ushort4*)&Nbf[(size_t)t * D2_SZ + D_SZ + tid * 4] = of;
  } else {
    const int id = bid - BT;            // 0..12287
    const int r = id >> 11;             // 0..5
    const int xb = id & 2047;
    const int i = xb * 256 + tid;       // < 524288
    const float* src;
    size_t off;
    switch (r) {
      case 0: src = Wtb; off = 0; break;
      case 1: src = Wpb; off = (size_t)1024 * KDIM; break;
      case 2: src = Wta; off = (size_t)2048 * KDIM; break;
      case 3: src = Wpa; off = (size_t)3072 * KDIM; break;
      case 4: src = Wgb; off = (size_t)4096 * KDIM; break;
      default: src = Wga; off = (size_t)6144 * KDIM; break;
    }
    {
      const float4 v = ((const float4*)src)[i];
      ushort4 o;
      o.x = f2bf(v.x); o.y = f2bf(v.y); o.z = f2bf(v.z); o.w = f2bf(v.w);
      ((ushort4*)(Wb + off))[i] = o;
    }
    if (r >= 4) {
      const int i2 = i + 524288;
      const float4 v = ((const float4*)src)[i2];
      ushort4 o;
      o.x = f2bf(v.x); o.y = f2bf(v.y); o.z = f2bf(v.z); o.w = f2bf(v.w);
      ((ushort4*)(Wb + off))[i2] = o;
    }
  }
}

// ---------------------------------------------------------------------------
// Kernel B: projection GEMM — faithful m201 8-phase port.
// 256x256 tile, BK=64, 8 waves (2Mx4N), 2 LDS buffers (even/odd K-tile),
// 4 half-tiles/K-tile (A0=mh0 rows, A1=mh1, B0=bit5:0 rows, B1=bit5:1),
// staged one per phase; quadrant MFMA order (mh0n0)(mh0n1)(mh1n1)(mh1n0)
// with A/B register reuse; vmcnt(6) ONLY at phases 4 and 8.
//
// Ledger (loads, 2/half-tile): prologue stages 7 halves (K0 all + K1 A0,B0,B1),
// vmcnt(6) -> K0 landed. Steady iter (k=2i): ph1 stages (k+1,A1), ph2-5
// stage (k+2,{A0,B0,B1,A1}), ph6-8 stage (k+3,{A0,B0,B1}).
//  ph4 vmcnt(6): outstanding = (k+2,{A0,B0,B1}) -> (k+1,A1) landed => K-tile
//    k+1 complete before ph5-8 reads it.
//  ph8 vmcnt(6): outstanding = (k+3,{A0,B0,B1}) -> (k+2,A1) landed => K-tile
//    k+2 complete before next-iter ph1-3 reads it.
//  Tail: it==15 -> ph4 vmcnt(0) ((31,A1) read at ph7), ph8 no wait.
// WAR: stage at phase p targets a region whose last ds_read completed
// (lgkm0 before MFMA) before phase p-1's trailing barrier; stage issues
// after that barrier. A0/B0 dead after ph1, B1 after ph2, A1 after ph3
// (per-K-tile), symmetric for ph5-8.
// Half-tile contiguity via row permutation implemented ONLY in the global
// source addressing (LDS dst stays linear — rule #21); XOR chunk swizzle
// (chunk ^= row&7) via pre-swizzled source + swizzled ds_read offset.
// ---------------------------------------------------------------------------
__global__ __launch_bounds__(512, 2) void gemm_fused(
    const unsigned short* __restrict__ X,
    const unsigned short* __restrict__ Wb,
    unsigned short* __restrict__ Cproj,
    unsigned short* __restrict__ Gbt,
    unsigned short* __restrict__ Gat) {
  __shared__ __align__(16) unsigned short lds[2 * 32768];  // 128 KiB
  const int tid = threadIdx.x;
  const int lane = tid & 63;
  const int w = tid >> 6;           // 0..7
  const int quad = lane >> 4;
  const int l15 = lane & 15;
  const int wm = (w >> 2) * 128;    // 2 waves in M
  const int wn = (w & 3) * 64;      // 4 waves in N

  // XCD-aware bijective swizzle: 256 blocks, 8 XCDs.
  const int bid = blockIdx.x;
  const int swz = (bid & 7) * 32 + (bid >> 3);
  const int m0 = (swz & 7) * 256;   // token tile
  const int be = swz >> 3;          // 0..31 E-tile
  const int e0 = be * 256;

  floatx4 acc[8][4];
#pragma unroll
  for (int mt = 0; mt < 8; ++mt)
#pragma unroll
    for (int nt = 0; nt < 4; ++nt) {
      floatx4 z = {0.f, 0.f, 0.f, 0.f};
      acc[mt][nt] = z;
    }

  // ---- staging addressing (slot s = tid + c*512; pr_local = s>>3, pc = s&7)
  const int gcs = (((tid & 7) ^ ((tid >> 3) & 7))) * 8;  // swizzled src chunk
  const unsigned short* sA0 = X + (size_t)(m0 + (tid >> 3)) * KDIM + gcs;
  const unsigned short* sA1 = X + (size_t)(m0 + 64 + (tid >> 3)) * KDIM + gcs;
  const int blr = (tid >> 8) * 64 + ((tid >> 3) & 31);
  const unsigned short* sB0 = Wb + (size_t)(e0 + blr) * KDIM + gcs;
  const unsigned short* sB1 = Wb + (size_t)(e0 + blr + 32) * KDIM + gcs;
  const size_t c1s = (size_t)128 * KDIM;   // +128 logical rows for c=1 load
  const int dA0 = tid * 8;                 // linear LDS dst (shorts)
  const int dA1 = 8192 + tid * 8;
  const int dB0 = 16384 + tid * 8;
  const int dB1 = 24576 + tid * 8;

  auto SA0 = [&](int kt) { if (kt < 32) { const int bb = (kt & 1) * 32768, ko = kt * 64;
      gload_lds16(sA0 + ko, &lds[bb + dA0]); gload_lds16(sA0 + c1s + ko, &lds[bb + dA0 + 4096]); } };
  auto SA1 = [&](int kt) { if (kt < 32) { const int bb = (kt & 1) * 32768, ko = kt * 64;
      gload_lds16(sA1 + ko, &lds[bb + dA1]); gload_lds16(sA1 + c1s + ko, &lds[bb + dA1 + 4096]); } };
  auto SB0 = [&](int kt) { if (kt < 32) { const int bb = (kt & 1) * 32768, ko = kt * 64;
      gload_lds16(sB0 + ko, &lds[bb + dB0]); gload_lds16(sB0 + c1s + ko, &lds[bb + dB0 + 4096]); } };
  auto SB1 = [&](int kt) { if (kt < 32) { const int bb = (kt & 1) * 32768, ko = kt * 64;
      gload_lds16(sB1 + ko, &lds[bb + dB1]); gload_lds16(sB1 + c1s + ko, &lds[bb + dB1 + 4096]); } };

  // ---- fragment read offsets (shorts). phys row * 64 + swizzled chunk * 8
  const int xc0 = ((quad ^ (l15 & 7))) * 8;        // kk=0
  const int xc1 = (((4 + quad) ^ (l15 & 7))) * 8;  // kk=1
  int prA64[8], pbB64[4];
#pragma unroll
  for (int mt = 0; mt < 8; ++mt)
    prA64[mt] = ((mt >> 2) * 128 + (w >> 2) * 64 + (mt & 3) * 16 + l15) * 64;
#pragma unroll
  for (int nt = 0; nt < 4; ++nt)
    pbB64[nt] = 16384 + ((nt >> 1) * 128 + (w & 3) * 32 + (nt & 1) * 16 + l15) * 64;

  // ---- prologue: K0 {A0,B0,B1,A1} + K1 {A0,B0,B1} = 14 loads
  SA0(0); SB0(0); SB1(0); SA1(0); SA0(1); SB0(1); SB1(1);
  __builtin_amdgcn_sched_barrier(0);
  asm volatile("s_waitcnt vmcnt(6)" ::: "memory");   // K-tile 0 landed
  __builtin_amdgcn_sched_barrier(0);
  __builtin_amdgcn_s_barrier();
  __builtin_amdgcn_sched_barrier(0);

  short8 aF[4][2], bL[2][2], bH[2][2];

#define LD(off) (*(const short8*)&lds[(off)])
#define MFMA16(M0, N0, AR, BR)                                                \
  __builtin_amdgcn_s_setprio(1);                                              \
  _Pragma("unroll")                                                           \
  for (int mt = 0; mt < 4; ++mt)                                              \
    _Pragma("unroll")                                                         \
    for (int nt = 0; nt < 2; ++nt)                                            \
      _Pragma("unroll")                                                       \
      for (int kk = 0; kk < 2; ++kk)                                          \
        acc[(M0) + mt][(N0) + nt] = __builtin_amdgcn_mfma_f32_16x16x32_bf16(  \
            AR[mt][kk], BR[nt][kk], acc[(M0) + mt][(N0) + nt], 0, 0, 0);      \
  __builtin_amdgcn_s_setprio(0);
#define BAR()                                                                 \
  __builtin_amdgcn_sched_barrier(0);                                          \
  __builtin_amdgcn_s_barrier();                                               \
  __builtin_amdgcn_sched_barrier(0);
#define LGKM0()                                                               \
  asm volatile("s_waitcnt lgkmcnt(0)" ::: "memory");                          \
  __builtin_amdgcn_sched_barrier(0);

  for (int it = 0; it < 16; ++it) {
    const int kt0 = it * 2;
    // ================= even K-tile (buf0) =================
    // ---- ph1: read A-mh0 (8) + B-nh0 (4); stage (kt0+1, A1)
#pragma unroll
    for (int mt = 0; mt < 4; ++mt) {
      aF[mt][0] = LD(prA64[mt] + xc0); aF[mt][1] = LD(prA64[mt] + xc1);
    }
#pragma unroll
    for (int nt = 0; nt < 2; ++nt) {
      bL[nt][0] = LD(pbB64[nt] + xc0); bL[nt][1] = LD(pbB64[nt] + xc1);
    }
    SA1(kt0 + 1);
    __builtin_amdgcn_sched_barrier(0);
    asm volatile("s_waitcnt lgkmcnt(8)" ::: "memory");
    BAR(); LGKM0();
    MFMA16(0, 0, aF, bL)
    BAR();
    // ---- ph2: read B-nh1 (4); stage (kt0+2, A0)
#pragma unroll
    for (int nt = 0; nt < 2; ++nt) {
      bH[nt][0] = LD(pbB64[2 + nt] + xc0); bH[nt][1] = LD(pbB64[2 + nt] + xc1);
    }
    SA0(kt0 + 2);
    BAR(); LGKM0();
    MFMA16(0, 2, aF, bH)
    BAR();
    // ---- ph3: read A-mh1 (8); stage (kt0+2, B0)
#pragma unroll
    for (int mt = 0; mt < 4; ++mt) {
      aF[mt][0] = LD(prA64[4 + mt] + xc0); aF[mt][1] = LD(prA64[4 + mt] + xc1);
    }
    SB0(kt0 + 2);
    BAR(); LGKM0();
    MFMA16(4, 2, aF, bH)
    BAR();
    // ---- ph4: no reads; stage (kt0+2, B1); vmcnt
    SB1(kt0 + 2);
    __builtin_amdgcn_sched_barrier(0);
    if (it < 15) {
      asm volatile("s_waitcnt vmcnt(6)" ::: "memory");
    } else {
      asm volatile("s_waitcnt vmcnt(0)" ::: "memory");
    }
    BAR();
    MFMA16(4, 0, aF, bL)
    BAR();
    // ================= odd K-tile (buf1) =================
    // ---- ph5: read A-mh0 + B-nh0 from buf1; stage (kt0+2, A1)
#pragma unroll
    for (int mt = 0; mt < 4; ++mt) {
      aF[mt][0] = LD(32768 + prA64[mt] + xc0);
      aF[mt][1] = LD(32768 + prA64[mt] + xc1);
    }
#pragma unroll
    for (int nt = 0; nt < 2; ++nt) {
      bL[nt][0] = LD(32768 + pbB64[nt] + xc0);
      bL[nt][1] = LD(32768 + pbB64[nt] + xc1);
    }
    SA1(kt0 + 2);
    __builtin_amdgcn_sched_barrier(0);
    asm volatile("s_waitcnt lgkmcnt(8)" ::: "memory");
    BAR(); LGKM0();
    MFMA16(0, 0, aF, bL)
    BAR();
    // ---- ph6: read B-nh1 buf1; stage (kt0+3, A0)
#pragma unroll
    for (int nt = 0; nt < 2; ++nt) {
      bH[nt][0] = LD(32768 + pbB64[2 + nt] + xc0);
      bH[nt][1] = LD(32768 + pbB64[2 + nt] + xc1);
    }
    SA0(kt0 + 3);
    BAR(); LGKM0();
    MFMA16(0, 2, aF, bH)
    BAR();
    // ---- ph7: read A-mh1 buf1; stage (kt0+3, B0)
#pragma unroll
    for (int mt = 0; mt < 4; ++mt) {
      aF[mt][0] = LD(32768 + prA64[4 + mt] + xc0);
      aF[mt][1] = LD(32768 + prA64[4 + mt] + xc1);
    }
    SB0(kt0 + 3);
    BAR(); LGKM0();
    MFMA16(4, 2, aF, bH)
    BAR();
    // ---- ph8: stage (kt0+3, B1); vmcnt
    SB1(kt0 + 3);
    __builtin_amdgcn_sched_barrier(0);
    if (it < 15) {
      asm volatile("s_waitcnt vmcnt(6)" ::: "memory");
    }
    BAR();
    MFMA16(4, 0, aF, bL)
    BAR();
  }
#undef LD
#undef MFMA16
#undef BAR
#undef LGKM0

  if (be < 16) {
#pragma unroll
    for (int mt = 0; mt < 8; ++mt)
#pragma unroll
      for (int nt = 0; nt < 4; ++nt) {
        const int col = e0 + wn + nt * 16 + l15;
#pragma unroll
        for (int r = 0; r < 4; ++r) {
          const int rowg = m0 + wm + mt * 16 + quad * 4 + r;
          Cproj[(size_t)rowg * EPROJ + col] = f2bf(acc[mt][nt][r]);
        }
      }
  } else {
    unsigned short* Gt = (be < 24) ? Gbt : Gat;
    const int fb = e0 - ((be < 24) ? 4096 : 6144);
#pragma unroll
    for (int mt = 0; mt < 8; ++mt)
#pragma unroll
      for (int nt = 0; nt < 4; ++nt) {
        const int f = fb + wn + nt * 16 + l15;
        const int tok0 = m0 + wm + mt * 16 + quad * 4;
        ushort4 o;
        o.x = f2bf(acc[mt][nt][0]); o.y = f2bf(acc[mt][nt][1]);
        o.z = f2bf(acc[mt][nt][2]); o.w = f2bf(acc[mt][nt][3]);
        *(ushort4*)&Gt[(size_t)f * BT + tok0] = o;
      }
  }
}

// ---------------------------------------------------------------------------
// Kernel 3: fused score. grid (16 batches, 2 branches, 2 j-chunks).
// ---------------------------------------------------------------------------
__global__ __launch_bounds__(256) void score_direct(
    const unsigned short* __restrict__ Cproj, unsigned short* __restrict__ Sbf) {
  const int b = blockIdx.x;
  const int br = blockIdx.y;
  const int jc = blockIdx.z;
  const int aoff = br ? 2048 : 0;   // ta : tb
  const int boff = aoff + 1024;     // pa : pb
  const int t0 = b * T_SZ;
  const int j0 = jc * 64;

  __shared__ __align__(16) unsigned short As[128 * 32];   // 8 KB
  __shared__ __align__(16) unsigned short Bs[64 * 32];    // 4 KB
  const int tid = threadIdx.x;
  const int lane = tid & 63;
  const int w = tid >> 6;
  const int wm = (w >> 1) * 64;    // i-offset (2 waves in M)
  const int wn = (w & 1) * 32;     // j-offset (2 waves in N)
  const int quad = lane >> 4;
  const int l15 = lane & 15;

  floatx4 acc[4][2];
#pragma unroll
  for (int mt = 0; mt < 4; ++mt)
#pragma unroll
    for (int nt = 0; nt < 2; ++nt) {
      floatx4 z = {0.f, 0.f, 0.f, 0.f};
      acc[mt][nt] = z;
    }

  const unsigned short* gA[2];
  unsigned short* lA[2];
#pragma unroll
  for (int c = 0; c < 2; ++c) {
    const int s = tid + c * 256;
    const int row = s >> 2;
    const int ccg = (s & 3) ^ ((row >> 1) & 3);
    gA[c] = Cproj + (size_t)(t0 + row) * EPROJ + aoff + ccg * 8;
    lA[c] = &As[(size_t)s * 8];
  }
  const unsigned short* gB;
  unsigned short* lB;
  {
    const int s = tid;
    const int row = s >> 2;
    const int ccg = (s & 3) ^ ((row >> 1) & 3);
    gB = Cproj + (size_t)(t0 + j0 + row) * EPROJ + boff + ccg * 8;
    lB = &Bs[(size_t)s * 8];
  }

  int aofs[4], bofs[2];
#pragma unroll
  for (int mt = 0; mt < 4; ++mt) {
    const int row = wm + mt * 16 + l15;
    aofs[mt] = row * 32 + ((quad ^ ((row >> 1) & 3)) * 8);
  }
#pragma unroll
  for (int nt = 0; nt < 2; ++nt) {
    const int row = wn + nt * 16 + l15;
    bofs[nt] = row * 32 + ((quad ^ ((row >> 1) & 3)) * 8);
  }

  for (int k0 = 0; k0 < D_SZ; k0 += 32) {   // K = 1024, 32 steps
    gload_lds16(gA[0] + k0, lA[0]);
    gload_lds16(gA[1] + k0, lA[1]);
    gload_lds16(gB + k0, lB);
    __syncthreads();
    short8 a[4], bb[2];
#pragma unroll
    for (int mt = 0; mt < 4; ++mt) a[mt] = *(const short8*)&As[aofs[mt]];
#pragma unroll
    for (int nt = 0; nt < 2; ++nt) bb[nt] = *(const short8*)&Bs[bofs[nt]];
#pragma unroll
    for (int mt = 0; mt < 4; ++mt)
#pragma unroll
      for (int nt = 0; nt < 2; ++nt)
        acc[mt][nt] = __builtin_amdgcn_mfma_f32_16x16x32_bf16(
            a[mt], bb[nt], acc[mt][nt], 0, 0, 0);
    __syncthreads();
  }

  const float scale = 0.022097086912079608f;  // 1/sqrt(2*1024)
  unsigned short* Sp = Sbf + ((size_t)(br * B_SZ + b)) * T_SZ * T_SZ;
#pragma unroll
  for (int mt = 0; mt < 4; ++mt)
#pragma unroll
    for (int nt = 0; nt < 2; ++nt) {
      const int j = j0 + wn + nt * 16 + l15;
#pragma unroll
      for (int r = 0; r < 4; ++r) {
        const int i = wm + mt * 16 + quad * 4 + r;
        const bool keep = br ? (j > i) : (j < i);
        Sp[(size_t)i * T_SZ + j] = f2bf(keep ? acc[mt][nt][r] * scale : 0.f);
      }
    }
}

// ---------------------------------------------------------------------------
// Kernel D: PV via MFMA, no LDS.
// ---------------------------------------------------------------------------
__global__ __launch_bounds__(256) void pv_mfma(
    const unsigned short* __restrict__ Nbf,
    const unsigned short* __restrict__ Sbf,
    const unsigned short* __restrict__ Gbt,
    const unsigned short* __restrict__ Gat,
    float* __restrict__ out) {
  const int ft = blockIdx.x;
  const int b = blockIdx.y;
  const int f0 = ft * 128;
  const int t0 = b * T_SZ;
  const int tid = threadIdx.x;
  const int lane = tid & 63;
  const int w = tid >> 6;
  const int wm = (w >> 1) * 64;   // token dim
  const int wn = (w & 1) * 64;    // f dim
  const int quad = lane >> 4;
  const int l15 = lane & 15;

  const unsigned short* Sb = Sbf + ((size_t)0 * B_SZ + b) * T_SZ * T_SZ;
  const unsigned short* Sa = Sbf + ((size_t)1 * B_SZ + b) * T_SZ * T_SZ;

  floatx4 acc[4][4];
#pragma unroll
  for (int mt = 0; mt < 4; ++mt)
#pragma unroll
    for (int nt = 0; nt < 4; ++nt) {
      floatx4 z = {0.f, 0.f, 0.f, 0.f};
      acc[mt][nt] = z;
    }

#pragma unroll
  for (int k0 = 0; k0 < T_SZ; k0 += 32) {
    short8 ab[4], aa[4], bb[4], ba[4];
#pragma unroll
    for (int mt = 0; mt < 4; ++mt) {
      const int i = wm + mt * 16 + l15;
      ab[mt] = *(const short8*)&Sb[(size_t)i * T_SZ + k0 + quad * 8];
      aa[mt] = *(const short8*)&Sa[(size_t)i * T_SZ + k0 + quad * 8];
    }
#pragma unroll
    for (int nt = 0; nt < 4; ++nt) {
      const int f = f0 + wn + nt * 16 + l15;
      bb[nt] = *(const short8*)&Gbt[(size_t)f * BT + t0 + k0 + quad * 8];
      ba[nt] = *(const short8*)&Gat[(size_t)f * BT + t0 + k0 + quad * 8];
    }
#pragma unroll
    for (int mt = 0; mt < 4; ++mt)
#pragma unroll
      for (int nt = 0; nt < 4; ++nt) {
        acc[mt][nt] = __builtin_amdgcn_mfma_f32_16x16x32_bf16(
            ab[mt], bb[nt], acc[mt][nt], 0, 0, 0);
        acc[mt][nt] = __builtin_amdgcn_mfma_f32_16x16x32_bf16(
            aa[mt], ba[nt], acc[mt][nt], 0, 0, 0);
      }
  }

#pragma unroll
  for (int mt = 0; mt < 4; ++mt)
#pragma unroll
    for (int nt = 0; nt < 4; ++nt) {
      const int f = f0 + wn + nt * 16 + l15;
#pragma unroll
      for (int r = 0; r < 4; ++r) {
        const int tok = t0 + wm + mt * 16 + quad * 4 + r;
        out[(size_t)tok * D2_SZ + f] =
            acc[mt][nt][r] + bf2f(Nbf[(size_t)tok * D2_SZ + f]);
      }
    }
}

// ---------------------------------------------------------------------------
extern "C" void kernel_launch(void* const* d_in, const int* in_sizes, int n_in,
                              void* d_out, int out_size, void* d_ws, size_t ws_size,
                              hipStream_t stream) {
  const float* feat = (const float*)d_in[0];
  const float* Wq  = (const float*)d_in[1];
  const float* Wtb = (const float*)d_in[2];
  const float* Wpb = (const float*)d_in[3];
  const float* Wgb = (const float*)d_in[4];  // dict order: gb before ta
  const float* Wta = (const float*)d_in[5];
  const float* Wpa = (const float*)d_in[6];
  const float* Wga = (const float*)d_in[7];
  float* out = (float*)d_out;

  unsigned short* ws = (unsigned short*)d_ws;
  unsigned short* Nbf   = ws;                                 // [2048][2048] bf16
  unsigned short* Wb    = Nbf + (size_t)BT * D2_SZ;           // [8192][2048] bf16
  unsigned short* Cproj = Wb + (size_t)EALL * KDIM;           // [2048][4096] bf16
  unsigned short* Gbt   = Cproj + (size_t)BT * EPROJ;         // [2048][2048] bf16
  unsigned short* Gat   = Gbt + (size_t)D2_SZ * BT;           // [2048][2048] bf16
  unsigned short* Sbf   = Gat + (size_t)D2_SZ * BT;           // [2][16][128][128] bf16

  prep_kernel<<<BT + 12288, 256, 0, stream>>>(feat, Wq, Wtb, Wpb, Wta, Wpa,
                                              Wgb, Wga, Nbf, Wb);
  gemm_fused<<<dim3(256), 512, 0, stream>>>(Nbf, Wb, Cproj, Gbt, Gat);
  score_direct<<<dim3(B_SZ, 2, 2), 256, 0, stream>>>(Cproj, Sbf);
  pv_mfma<<<dim3(D2_SZ / 128, B_SZ), 256, 0, stream>>>(Nbf, Sbf, Gbt, Gat, out);
}

// Round 9
// 290.265 us; speedup vs baseline: 1.0566x; 1.0134x over previous
//
#include <hip/hip_runtime.h>
#include <hip/hip_bf16.h>
#include <math.h>

#define B_SZ 16
#define T_SZ 128
#define N_P 12
#define D_SZ 1024
#define D2_SZ 2048
#define BT 2048          // B*T tokens
#define KDIM 2048        // inner dim of projections (2D)
#define EALL 8192        // 4*1024 (tb,pb,ta,pa) + 2*2048 (gb,ga)
#define EPROJ 4096       // tb|pb|ta|pa row width

typedef __attribute__((ext_vector_type(8))) short short8;    // 8 bf16 = 4 VGPRs
typedef __attribute__((ext_vector_type(4))) float floatx4;   // MFMA C/D

__device__ inline void gload_lds16(const void* g, void* l) {
  __builtin_amdgcn_global_load_lds(
      (const __attribute__((address_space(1))) void*)g,
      (__attribute__((address_space(3))) void*)l, 16, 0, 0);
}

__device__ inline unsigned short f2bf(float x) {
  union { __hip_bfloat16 h; unsigned short u; } cv;
  cv.h = __float2bfloat16(x);
  return cv.u;
}
__device__ inline float bf2f(unsigned short u) {
  return __uint_as_float(((unsigned)u) << 16);
}

// ---------------------------------------------------------------------------
// Kernel 1 (merged): blocks [0, BT) build n = [g ; max] per token;
// blocks [BT, BT+12288) convert the 6 weight matrices to bf16.
// Wb row order: [tb | pb | ta | pa | gb | ga]
// ---------------------------------------------------------------------------
__global__ __launch_bounds__(256) void prep_kernel(
    const float* __restrict__ feat, const float* __restrict__ Wq,
    const float* __restrict__ Wtb, const float* __restrict__ Wpb,
    const float* __restrict__ Wta, const float* __restrict__ Wpa,
    const float* __restrict__ Wgb, const float* __restrict__ Wga,
    unsigned short* __restrict__ Nbf, unsigned short* __restrict__ Wb) {
  const int bid = blockIdx.x;
  const int tid = threadIdx.x;
  if (bid < BT) {
    const int t = bid;
    const float4* fb4 = (const float4*)(feat + (size_t)t * N_P * D_SZ);
    const float4* wq4 = (const float4*)Wq;

    float4 q = {0.f, 0.f, 0.f, 0.f};
#pragma unroll
    for (int m = 0; m < N_P; ++m) {
      const float4 v = wq4[m * 256 + tid];
      q.x += v.x; q.y += v.y; q.z += v.z; q.w += v.w;
    }

    float4 fv[N_P];
    float part[N_P];
#pragma unroll
    for (int n = 0; n < N_P; ++n) {
      const float4 f = fb4[n * 256 + tid];
      fv[n] = f;
      part[n] = f.x * q.x + f.y * q.y + f.z * q.z + f.w * q.w;
    }

    __shared__ float wred[N_P * 4];
    const int lane = tid & 63;
    const int wave = tid >> 6;
#pragma unroll
    for (int n = 0; n < N_P; ++n) {
      float v = part[n];
#pragma unroll
      for (int off = 32; off; off >>= 1) v += __shfl_down(v, off);
      if (lane == 0) wred[n * 4 + wave] = v;
    }
    __syncthreads();

    float w[N_P];
#pragma unroll
    for (int n = 0; n < N_P; ++n)
      w[n] = wred[n * 4 + 0] + wred[n * 4 + 1] + wred[n * 4 + 2] +
             wred[n * 4 + 3];

    float4 g = {0.f, 0.f, 0.f, 0.f};
    float4 fm = {-INFINITY, -INFINITY, -INFINITY, -INFINITY};
#pragma unroll
    for (int n = 0; n < N_P; ++n) {
      const float4 f = fv[n];
      g.x += w[n] * f.x; g.y += w[n] * f.y; g.z += w[n] * f.z;
      g.w += w[n] * f.w;
      fm.x = fmaxf(fm.x, f.x); fm.y = fmaxf(fm.y, f.y);
      fm.z = fmaxf(fm.z, f.z); fm.w = fmaxf(fm.w, f.w);
    }
    ushort4 og, of;
    og.x = f2bf(g.x); og.y = f2bf(g.y); og.z = f2bf(g.z); og.w = f2bf(g.w);
    of.x = f2bf(fm.x); of.y = f2bf(fm.y); of.z = f2bf(fm.z); of.w = f2bf(fm.w);
    *(ushort4*)&Nbf[(size_t)t * D2_SZ + tid * 4] = og;
    *(ushort4*)&Nbf[(size_t)t * D2_SZ + D_SZ + tid * 4] = of;
  } else {
    const int id = bid - BT;            // 0..12287
    const int r = id >> 11;             // 0..5
    const int xb = id & 2047;
    const int i = xb * 256 + tid;       // < 524288
    const float* src;
    size_t off;
    switch (r) {
      case 0: src = Wtb; off = 0; break;
      case 1: src = Wpb; off = (size_t)1024 * KDIM; break;
      case 2: src = Wta; off = (size_t)2048 * KDIM; break;
      case 3: src = Wpa; off = (size_t)3072 * KDIM; break;
      case 4: src = Wgb; off = (size_t)4096 * KDIM; break;
      default: src = Wga; off = (size_t)6144 * KDIM; break;
    }
    {
      const float4 v = ((const float4*)src)[i];
      ushort4 o;
      o.x = f2bf(v.x); o.y = f2bf(v.y); o.z = f2bf(v.z); o.w = f2bf(v.w);
      ((ushort4*)(Wb + off))[i] = o;
    }
    if (r >= 4) {
      const int i2 = i + 524288;
      const float4 v = ((const float4*)src)[i2];
      ushort4 o;
      o.x = f2bf(v.x); o.y = f2bf(v.y); o.z = f2bf(v.z); o.w = f2bf(v.w);
      ((ushort4*)(Wb + off))[i2] = o;
    }
  }
}

// ---------------------------------------------------------------------------
// Kernel B: projection GEMM — m201 8-phase port (R8, session-best: 68 µs).
// FROZEN — do not modify.
// ---------------------------------------------------------------------------
__global__ __launch_bounds__(512, 2) void gemm_fused(
    const unsigned short* __restrict__ X,
    const unsigned short* __restrict__ Wb,
    unsigned short* __restrict__ Cproj,
    unsigned short* __restrict__ Gbt,
    unsigned short* __restrict__ Gat) {
  __shared__ __align__(16) unsigned short lds[2 * 32768];  // 128 KiB
  const int tid = threadIdx.x;
  const int lane = tid & 63;
  const int w = tid >> 6;           // 0..7
  const int quad = lane >> 4;
  const int l15 = lane & 15;
  const int wm = (w >> 2) * 128;    // 2 waves in M
  const int wn = (w & 3) * 64;      // 4 waves in N

  const int bid = blockIdx.x;
  const int swz = (bid & 7) * 32 + (bid >> 3);
  const int m0 = (swz & 7) * 256;   // token tile
  const int be = swz >> 3;          // 0..31 E-tile
  const int e0 = be * 256;

  floatx4 acc[8][4];
#pragma unroll
  for (int mt = 0; mt < 8; ++mt)
#pragma unroll
    for (int nt = 0; nt < 4; ++nt) {
      floatx4 z = {0.f, 0.f, 0.f, 0.f};
      acc[mt][nt] = z;
    }

  const int gcs = (((tid & 7) ^ ((tid >> 3) & 7))) * 8;  // swizzled src chunk
  const unsigned short* sA0 = X + (size_t)(m0 + (tid >> 3)) * KDIM + gcs;
  const unsigned short* sA1 = X + (size_t)(m0 + 64 + (tid >> 3)) * KDIM + gcs;
  const int blr = (tid >> 8) * 64 + ((tid >> 3) & 31);
  const unsigned short* sB0 = Wb + (size_t)(e0 + blr) * KDIM + gcs;
  const unsigned short* sB1 = Wb + (size_t)(e0 + blr + 32) * KDIM + gcs;
  const size_t c1s = (size_t)128 * KDIM;   // +128 logical rows for c=1 load
  const int dA0 = tid * 8;                 // linear LDS dst (shorts)
  const int dA1 = 8192 + tid * 8;
  const int dB0 = 16384 + tid * 8;
  const int dB1 = 24576 + tid * 8;

  auto SA0 = [&](int kt) { if (kt < 32) { const int bb = (kt & 1) * 32768, ko = kt * 64;
      gload_lds16(sA0 + ko, &lds[bb + dA0]); gload_lds16(sA0 + c1s + ko, &lds[bb + dA0 + 4096]); } };
  auto SA1 = [&](int kt) { if (kt < 32) { const int bb = (kt & 1) * 32768, ko = kt * 64;
      gload_lds16(sA1 + ko, &lds[bb + dA1]); gload_lds16(sA1 + c1s + ko, &lds[bb + dA1 + 4096]); } };
  auto SB0 = [&](int kt) { if (kt < 32) { const int bb = (kt & 1) * 32768, ko = kt * 64;
      gload_lds16(sB0 + ko, &lds[bb + dB0]); gload_lds16(sB0 + c1s + ko, &lds[bb + dB0 + 4096]); } };
  auto SB1 = [&](int kt) { if (kt < 32) { const int bb = (kt & 1) * 32768, ko = kt * 64;
      gload_lds16(sB1 + ko, &lds[bb + dB1]); gload_lds16(sB1 + c1s + ko, &lds[bb + dB1 + 4096]); } };

  const int xc0 = ((quad ^ (l15 & 7))) * 8;        // kk=0
  const int xc1 = (((4 + quad) ^ (l15 & 7))) * 8;  // kk=1
  int prA64[8], pbB64[4];
#pragma unroll
  for (int mt = 0; mt < 8; ++mt)
    prA64[mt] = ((mt >> 2) * 128 + (w >> 2) * 64 + (mt & 3) * 16 + l15) * 64;
#pragma unroll
  for (int nt = 0; nt < 4; ++nt)
    pbB64[nt] = 16384 + ((nt >> 1) * 128 + (w & 3) * 32 + (nt & 1) * 16 + l15) * 64;

  SA0(0); SB0(0); SB1(0); SA1(0); SA0(1); SB0(1); SB1(1);
  __builtin_amdgcn_sched_barrier(0);
  asm volatile("s_waitcnt vmcnt(6)" ::: "memory");   // K-tile 0 landed
  __builtin_amdgcn_sched_barrier(0);
  __builtin_amdgcn_s_barrier();
  __builtin_amdgcn_sched_barrier(0);

  short8 aF[4][2], bL[2][2], bH[2][2];

#define LD(off) (*(const short8*)&lds[(off)])
#define MFMA16(M0, N0, AR, BR)                                                \
  __builtin_amdgcn_s_setprio(1);                                              \
  _Pragma("unroll")                                                           \
  for (int mt = 0; mt < 4; ++mt)                                              \
    _Pragma("unroll")                                                         \
    for (int nt = 0; nt < 2; ++nt)                                            \
      _Pragma("unroll")                                                       \
      for (int kk = 0; kk < 2; ++kk)                                          \
        acc[(M0) + mt][(N0) + nt] = __builtin_amdgcn_mfma_f32_16x16x32_bf16(  \
            AR[mt][kk], BR[nt][kk], acc[(M0) + mt][(N0) + nt], 0, 0, 0);      \
  __builtin_amdgcn_s_setprio(0);
#define BAR()                                                                 \
  __builtin_amdgcn_sched_barrier(0);                                          \
  __builtin_amdgcn_s_barrier();                                               \
  __builtin_amdgcn_sched_barrier(0);
#define LGKM0()                                                               \
  asm volatile("s_waitcnt lgkmcnt(0)" ::: "memory");                          \
  __builtin_amdgcn_sched_barrier(0);

  for (int it = 0; it < 16; ++it) {
    const int kt0 = it * 2;
    // ================= even K-tile (buf0) =================
#pragma unroll
    for (int mt = 0; mt < 4; ++mt) {
      aF[mt][0] = LD(prA64[mt] + xc0); aF[mt][1] = LD(prA64[mt] + xc1);
    }
#pragma unroll
    for (int nt = 0; nt < 2; ++nt) {
      bL[nt][0] = LD(pbB64[nt] + xc0); bL[nt][1] = LD(pbB64[nt] + xc1);
    }
    SA1(kt0 + 1);
    __builtin_amdgcn_sched_barrier(0);
    asm volatile("s_waitcnt lgkmcnt(8)" ::: "memory");
    BAR(); LGKM0();
    MFMA16(0, 0, aF, bL)
    BAR();
#pragma unroll
    for (int nt = 0; nt < 2; ++nt) {
      bH[nt][0] = LD(pbB64[2 + nt] + xc0); bH[nt][1] = LD(pbB64[2 + nt] + xc1);
    }
    SA0(kt0 + 2);
    BAR(); LGKM0();
    MFMA16(0, 2, aF, bH)
    BAR();
#pragma unroll
    for (int mt = 0; mt < 4; ++mt) {
      aF[mt][0] = LD(prA64[4 + mt] + xc0); aF[mt][1] = LD(prA64[4 + mt] + xc1);
    }
    SB0(kt0 + 2);
    BAR(); LGKM0();
    MFMA16(4, 2, aF, bH)
    BAR();
    SB1(kt0 + 2);
    __builtin_amdgcn_sched_barrier(0);
    if (it < 15) {
      asm volatile("s_waitcnt vmcnt(6)" ::: "memory");
    } else {
      asm volatile("s_waitcnt vmcnt(0)" ::: "memory");
    }
    BAR();
    MFMA16(4, 0, aF, bL)
    BAR();
    // ================= odd K-tile (buf1) =================
#pragma unroll
    for (int mt = 0; mt < 4; ++mt) {
      aF[mt][0] = LD(32768 + prA64[mt] + xc0);
      aF[mt][1] = LD(32768 + prA64[mt] + xc1);
    }
#pragma unroll
    for (int nt = 0; nt < 2; ++nt) {
      bL[nt][0] = LD(32768 + pbB64[nt] + xc0);
      bL[nt][1] = LD(32768 + pbB64[nt] + xc1);
    }
    SA1(kt0 + 2);
    __builtin_amdgcn_sched_barrier(0);
    asm volatile("s_waitcnt lgkmcnt(8)" ::: "memory");
    BAR(); LGKM0();
    MFMA16(0, 0, aF, bL)
    BAR();
#pragma unroll
    for (int nt = 0; nt < 2; ++nt) {
      bH[nt][0] = LD(32768 + pbB64[2 + nt] + xc0);
      bH[nt][1] = LD(32768 + pbB64[2 + nt] + xc1);
    }
    SA0(kt0 + 3);
    BAR(); LGKM0();
    MFMA16(0, 2, aF, bH)
    BAR();
#pragma unroll
    for (int mt = 0; mt < 4; ++mt) {
      aF[mt][0] = LD(32768 + prA64[4 + mt] + xc0);
      aF[mt][1] = LD(32768 + prA64[4 + mt] + xc1);
    }
    SB0(kt0 + 3);
    BAR(); LGKM0();
    MFMA16(4, 2, aF, bH)
    BAR();
    SB1(kt0 + 3);
    __builtin_amdgcn_sched_barrier(0);
    if (it < 15) {
      asm volatile("s_waitcnt vmcnt(6)" ::: "memory");
    }
    BAR();
    MFMA16(4, 0, aF, bL)
    BAR();
  }
#undef LD
#undef MFMA16
#undef BAR
#undef LGKM0

  if (be < 16) {
#pragma unroll
    for (int mt = 0; mt < 8; ++mt)
#pragma unroll
      for (int nt = 0; nt < 4; ++nt) {
        const int col = e0 + wn + nt * 16 + l15;
#pragma unroll
        for (int r = 0; r < 4; ++r) {
          const int rowg = m0 + wm + mt * 16 + quad * 4 + r;
          Cproj[(size_t)rowg * EPROJ + col] = f2bf(acc[mt][nt][r]);
        }
      }
  } else {
    unsigned short* Gt = (be < 24) ? Gbt : Gat;
    const int fb = e0 - ((be < 24) ? 4096 : 6144);
#pragma unroll
    for (int mt = 0; mt < 8; ++mt)
#pragma unroll
      for (int nt = 0; nt < 4; ++nt) {
        const int f = fb + wn + nt * 16 + l15;
        const int tok0 = m0 + wm + mt * 16 + quad * 4;
        ushort4 o;
        o.x = f2bf(acc[mt][nt][0]); o.y = f2bf(acc[mt][nt][1]);
        o.z = f2bf(acc[mt][nt][2]); o.w = f2bf(acc[mt][nt][3]);
        *(ushort4*)&Gt[(size_t)f * BT + tok0] = o;
      }
  }
}

// ---------------------------------------------------------------------------
// Kernel 3: fused score with ring-of-3 pipeline + counted vmcnt (R7-verified
// pattern). grid (16 batches, 2 branches, 2 j-chunks), 128(i)x64(j), K=1024.
// Ledger: 3 gload_lds/thread/step, prefetch distance 2. Prologue stages
// slots {0,1} (6 loads) -> vmcnt(3) = slot0 landed. Steady: stage(t+2) ->
// outstanding {t+1:3, t+2:3} -> vmcnt(3) = slot t+1 landed; barrier makes
// it workgroup-wide. Tail: t=30 -> vmcnt(0); t=31 -> none. WAR: stage(t+2)
// overwrites the slot read at step t-1, drained before t-1's end barrier.
// ---------------------------------------------------------------------------
__global__ __launch_bounds__(256) void score_direct(
    const unsigned short* __restrict__ Cproj, unsigned short* __restrict__ Sbf) {
  const int b = blockIdx.x;
  const int br = blockIdx.y;
  const int jc = blockIdx.z;
  const int aoff = br ? 2048 : 0;   // ta : tb
  const int boff = aoff + 1024;     // pa : pb
  const int t0 = b * T_SZ;
  const int j0 = jc * 64;

  // 3 slots x (A 8KB + B 4KB) = 36 KB. Slot layout: [A 4096 shorts][B 2048].
  __shared__ __align__(16) unsigned short lds[3 * 6144];
  const int tid = threadIdx.x;
  const int lane = tid & 63;
  const int w = tid >> 6;
  const int wm = (w >> 1) * 64;    // i-offset (2 waves in M)
  const int wn = (w & 1) * 32;     // j-offset (2 waves in N)
  const int quad = lane >> 4;
  const int l15 = lane & 15;

  floatx4 acc[4][2];
#pragma unroll
  for (int mt = 0; mt < 4; ++mt)
#pragma unroll
    for (int nt = 0; nt < 2; ++nt) {
      floatx4 z = {0.f, 0.f, 0.f, 0.f};
      acc[mt][nt] = z;
    }

  const unsigned short* gA[2];
  int dA[2];
#pragma unroll
  for (int c = 0; c < 2; ++c) {
    const int s = tid + c * 256;
    const int row = s >> 2;
    const int ccg = (s & 3) ^ ((row >> 1) & 3);
    gA[c] = Cproj + (size_t)(t0 + row) * EPROJ + aoff + ccg * 8;
    dA[c] = s * 8;
  }
  const unsigned short* gB;
  int dB;
  {
    const int s = tid;
    const int row = s >> 2;
    const int ccg = (s & 3) ^ ((row >> 1) & 3);
    gB = Cproj + (size_t)(t0 + j0 + row) * EPROJ + boff + ccg * 8;
    dB = 4096 + s * 8;
  }

  int aofs[4], bofs[2];
#pragma unroll
  for (int mt = 0; mt < 4; ++mt) {
    const int row = wm + mt * 16 + l15;
    aofs[mt] = row * 32 + ((quad ^ ((row >> 1) & 3)) * 8);
  }
#pragma unroll
  for (int nt = 0; nt < 2; ++nt) {
    const int row = wn + nt * 16 + l15;
    bofs[nt] = 4096 + row * 32 + ((quad ^ ((row >> 1) & 3)) * 8);
  }

  auto STAGE = [&](int t, int sb) {
    const int k0_ = t * 32;
    gload_lds16(gA[0] + k0_, &lds[sb + dA[0]]);
    gload_lds16(gA[1] + k0_, &lds[sb + dA[1]]);
    gload_lds16(gB + k0_, &lds[sb + dB]);
  };

  int s0 = 0, s1 = 6144, s2 = 12288;

  STAGE(0, s0); STAGE(1, s1);
  __builtin_amdgcn_sched_barrier(0);
  asm volatile("s_waitcnt vmcnt(3)" ::: "memory");
  __builtin_amdgcn_sched_barrier(0);
  __builtin_amdgcn_s_barrier();
  __builtin_amdgcn_sched_barrier(0);

  for (int t = 0; t < 32; ++t) {   // K = 1024, 32 steps
    short8 a[4], bb[2];
#pragma unroll
    for (int mt = 0; mt < 4; ++mt) a[mt] = *(const short8*)&lds[s0 + aofs[mt]];
#pragma unroll
    for (int nt = 0; nt < 2; ++nt) bb[nt] = *(const short8*)&lds[s0 + bofs[nt]];
    if (t + 2 < 32) STAGE(t + 2, s2);
    __builtin_amdgcn_s_setprio(1);
#pragma unroll
    for (int mt = 0; mt < 4; ++mt)
#pragma unroll
      for (int nt = 0; nt < 2; ++nt)
        acc[mt][nt] = __builtin_amdgcn_mfma_f32_16x16x32_bf16(
            a[mt], bb[nt], acc[mt][nt], 0, 0, 0);
    __builtin_amdgcn_s_setprio(0);
    __builtin_amdgcn_sched_barrier(0);
    if (t + 2 < 32) {
      asm volatile("s_waitcnt vmcnt(3)" ::: "memory");
    } else if (t + 1 < 32) {
      asm volatile("s_waitcnt vmcnt(0)" ::: "memory");
    }
    __builtin_amdgcn_sched_barrier(0);
    if (t + 1 < 32) {
      __builtin_amdgcn_s_barrier();
      __builtin_amdgcn_sched_barrier(0);
    }
    const int tmp = s0; s0 = s1; s1 = s2; s2 = tmp;
  }

  const float scale = 0.022097086912079608f;  // 1/sqrt(2*1024)
  unsigned short* Sp = Sbf + ((size_t)(br * B_SZ + b)) * T_SZ * T_SZ;
#pragma unroll
  for (int mt = 0; mt < 4; ++mt)
#pragma unroll
    for (int nt = 0; nt < 2; ++nt) {
      const int j = j0 + wn + nt * 16 + l15;
#pragma unroll
      for (int r = 0; r < 4; ++r) {
        const int i = wm + mt * 16 + quad * 4 + r;
        const bool keep = br ? (j > i) : (j < i);
        Sp[(size_t)i * T_SZ + j] = f2bf(keep ? acc[mt][nt][r] * scale : 0.f);
      }
    }
}

// ---------------------------------------------------------------------------
// Kernel D: PV via MFMA, no LDS. NOW: 64-f tiles -> grid (32,16) = 512 blocks
// = 2 blocks/CU for latency overlap (S/G re-reads are L2-resident, so no
// FETCH penalty unlike the R7 gemm split).
// ---------------------------------------------------------------------------
__global__ __launch_bounds__(256) void pv_mfma(
    const unsigned short* __restrict__ Nbf,
    const unsigned short* __restrict__ Sbf,
    const unsigned short* __restrict__ Gbt,
    const unsigned short* __restrict__ Gat,
    float* __restrict__ out) {
  const int ft = blockIdx.x;
  const int b = blockIdx.y;
  const int f0 = ft * 64;
  const int t0 = b * T_SZ;
  const int tid = threadIdx.x;
  const int lane = tid & 63;
  const int w = tid >> 6;
  const int wm = (w >> 1) * 64;   // token dim (2 waves)
  const int wn = (w & 1) * 32;    // f dim (2 waves x 32)
  const int quad = lane >> 4;
  const int l15 = lane & 15;

  const unsigned short* Sb = Sbf + ((size_t)0 * B_SZ + b) * T_SZ * T_SZ;
  const unsigned short* Sa = Sbf + ((size_t)1 * B_SZ + b) * T_SZ * T_SZ;

  floatx4 acc[4][2];
#pragma unroll
  for (int mt = 0; mt < 4; ++mt)
#pragma unroll
    for (int nt = 0; nt < 2; ++nt) {
      floatx4 z = {0.f, 0.f, 0.f, 0.f};
      acc[mt][nt] = z;
    }

#pragma unroll
  for (int k0 = 0; k0 < T_SZ; k0 += 32) {
    short8 ab[4], aa[4], bb[2], ba[2];
#pragma unroll
    for (int mt = 0; mt < 4; ++mt) {
      const int i = wm + mt * 16 + l15;
      ab[mt] = *(const short8*)&Sb[(size_t)i * T_SZ + k0 + quad * 8];
      aa[mt] = *(const short8*)&Sa[(size_t)i * T_SZ + k0 + quad * 8];
    }
#pragma unroll
    for (int nt = 0; nt < 2; ++nt) {
      const int f = f0 + wn + nt * 16 + l15;
      bb[nt] = *(const short8*)&Gbt[(size_t)f * BT + t0 + k0 + quad * 8];
      ba[nt] = *(const short8*)&Gat[(size_t)f * BT + t0 + k0 + quad * 8];
    }
#pragma unroll
    for (int mt = 0; mt < 4; ++mt)
#pragma unroll
      for (int nt = 0; nt < 2; ++nt) {
        acc[mt][nt] = __builtin_amdgcn_mfma_f32_16x16x32_bf16(
            ab[mt], bb[nt], acc[mt][nt], 0, 0, 0);
        acc[mt][nt] = __builtin_amdgcn_mfma_f32_16x16x32_bf16(
            aa[mt], ba[nt], acc[mt][nt], 0, 0, 0);
      }
  }

#pragma unroll
  for (int mt = 0; mt < 4; ++mt)
#pragma unroll
    for (int nt = 0; nt < 2; ++nt) {
      const int f = f0 + wn + nt * 16 + l15;
#pragma unroll
      for (int r = 0; r < 4; ++r) {
        const int tok = t0 + wm + mt * 16 + quad * 4 + r;
        out[(size_t)tok * D2_SZ + f] =
            acc[mt][nt][r] + bf2f(Nbf[(size_t)tok * D2_SZ + f]);
      }
    }
}

// ---------------------------------------------------------------------------
extern "C" void kernel_launch(void* const* d_in, const int* in_sizes, int n_in,
                              void* d_out, int out_size, void* d_ws, size_t ws_size,
                              hipStream_t stream) {
  const float* feat = (const float*)d_in[0];
  const float* Wq  = (const float*)d_in[1];
  const float* Wtb = (const float*)d_in[2];
  const float* Wpb = (const float*)d_in[3];
  const float* Wgb = (const float*)d_in[4];  // dict order: gb before ta
  const float* Wta = (const float*)d_in[5];
  const float* Wpa = (const float*)d_in[6];
  const float* Wga = (const float*)d_in[7];
  float* out = (float*)d_out;

  unsigned short* ws = (unsigned short*)d_ws;
  unsigned short* Nbf   = ws;                                 // [2048][2048] bf16
  unsigned short* Wb    = Nbf + (size_t)BT * D2_SZ;           // [8192][2048] bf16
  unsigned short* Cproj = Wb + (size_t)EALL * KDIM;           // [2048][4096] bf16
  unsigned short* Gbt   = Cproj + (size_t)BT * EPROJ;         // [2048][2048] bf16
  unsigned short* Gat   = Gbt + (size_t)D2_SZ * BT;           // [2048][2048] bf16
  unsigned short* Sbf   = Gat + (size_t)D2_SZ * BT;           // [2][16][128][128] bf16

  prep_kernel<<<BT + 12288, 256, 0, stream>>>(feat, Wq, Wtb, Wpb, Wta, Wpa,
                                              Wgb, Wga, Nbf, Wb);
  gemm_fused<<<dim3(256), 512, 0, stream>>>(Nbf, Wb, Cproj, Gbt, Gat);
  score_direct<<<dim3(B_SZ, 2, 2), 256, 0, stream>>>(Cproj, Sbf);
  pv_mfma<<<dim3(D2_SZ / 64, B_SZ), 256, 0, stream>>>(Nbf, Sbf, Gbt, Gat, out);
}